// Round 1
// 3588.403 us; speedup vs baseline: 1.7001x; 1.7001x over previous
//
#include <hip/hip_runtime.h>

// ---------------------------------------------------------------------------
// VQ-VAE encoder — numpy-pairwise fp32 emulation (R12 semantics, PASSING).
// R14: latency restructure of conv2/conv3 ONLY. Bit-exactness invariant:
// identical products, identical per-accumulator op order, identical tree.
// Changes vs R13:
//  - staging decode (divisions, bounds, lds offsets) hoisted out of leaf loop
//  - input staging split: issue global->reg loads for leaf L+1 BEFORE the
//    leaf-L compute block; ds_write regs->LDS after the barrier (T14 split)
//  - weight staging via __builtin_amdgcn_global_load_lds (width 16) into a
//    double-buffered Wl[2] (linear [cl][f][co] layout is lane-ordered)
//  - 2 barriers/leaf kept, but no global-latency exposure at either
// conv1/conv4/vq unchanged (each ~10us class, 1 block/CU, negligible).
// d_out: z_q_st[262144] | loss[1] | idx[65536]
// ---------------------------------------------------------------------------

#define TREE8(r) ((((r)[0]+(r)[1])+((r)[2]+(r)[3]))+((((r)[4]+(r)[5]))+((r)[6]+(r)[7])))

// async global->LDS for one 8ci weight leaf: 4096 floats, 16 chunks of 256.
// wave w issues chunks w*4..w*4+3; lane l covers floats 4l..4l+3 of chunk.
// LDS linear idx e <-> (cl=e>>9, f=(e>>5)&15, co=e&31); src co-contiguous.
__device__ __forceinline__ void stage_w8(const float* __restrict__ src0,
                                         float* dst0, int wid, int lane) {
#pragma unroll
    for (int it = 0; it < 4; ++it) {
        int j = wid * 4 + it;
        int e = j * 256 + lane * 4;
        int co = e & 31, f = (e >> 5) & 15, cl = e >> 9;
        const float* src = src0 + cl * 2048 + f * 128 + co;
        __builtin_amdgcn_global_load_lds(
            (const __attribute__((address_space(1))) void*)src,
            (__attribute__((address_space(3))) void*)(dst0 + j * 256),
            16, 0, 0);
    }
}

// ---------------- weight transform: wT[ci][f][co] from w[co][ci][f]
__global__ __launch_bounds__(256) void wt_kernel(
    const float* __restrict__ w2, const float* __restrict__ w3,
    float* __restrict__ wT2, float* __restrict__ wT3) {
    int g = blockIdx.x * 256 + threadIdx.x;
    if (g < 131072) {             // conv2: ci 64, f 16, co 128
        int co = g & 127, f = (g >> 7) & 15, ci = g >> 11;
        wT2[g] = w2[co * 1024 + ci * 16 + f];
    }
    int g2 = g - 131072;
    if (g2 >= 0 && g2 < 262144) { // conv3: ci 128, f 16, co 128
        int co = g2 & 127, f = (g2 >> 7) & 15, ci = g2 >> 11;
        wT3[g2] = w3[co * 2048 + ci * 16 + f];
    }
}

// ---------------- conv1: 1->64, 4x4, s2, p1 (unchanged from R12)
__global__ __launch_bounds__(256) void conv1_kernel(
    const float* __restrict__ x, const float* __restrict__ w1,
    const float* __restrict__ b1, float* __restrict__ h1) {
#pragma clang fp contract(off)
    __shared__ __align__(16) float wl[64 * 16];
    __shared__ float bl[64];
    const int tid = threadIdx.x;
    {
        const float4* src = (const float4*)w1;
        ((float4*)wl)[tid] = src[tid];
        if (tid < 64) bl[tid] = b1[tid];
    }
    __syncthreads();

    const int oxl = tid & 63, oyq = tid >> 6;
    const int img = blockIdx.z;
    const int ox  = blockIdx.x * 64 + oxl;
    const int oy0 = blockIdx.y * 16 + oyq * 4;
    const float* xi = x + (size_t)img * 262144;

    float in[10][4];
    const int ix0 = 2 * ox - 1;
    const int iy0 = 2 * oy0 - 1;
#pragma unroll
    for (int r = 0; r < 10; ++r) {
        int iy = iy0 + r;
#pragma unroll
        for (int k = 0; k < 4; ++k) {
            int ixx = ix0 + k;
            bool ok = ((unsigned)iy < 512u) && ((unsigned)ixx < 512u);
            in[r][k] = ok ? xi[iy * 512 + ixx] : 0.f;
        }
    }

    float* outp = h1 + (size_t)img * 4194304;
#pragma unroll
    for (int c = 0; c < 64; ++c) {
        const float* wp = &wl[c * 16];
        float bv = bl[c];
#pragma unroll
        for (int p = 0; p < 4; ++p) {
            float a[16];
#pragma unroll
            for (int f = 0; f < 16; ++f)
                a[f] = in[2 * p + (f >> 2)][f & 3] * wp[f];
            float r[8];
#pragma unroll
            for (int j = 0; j < 8; ++j) r[j] = a[j] + a[8 + j];
            float tot = TREE8(r);
            outp[(size_t)c * 65536 + (size_t)(oy0 + p) * 256 + ox] =
                fmaxf(tot + bv, 0.f);
        }
    }
}

// ---------------- conv2: 64->128, 4x4, s2, p1, 256->128. K=1024, 8 leaves.
// tile 32ox x 32co x 1oy; async staging (see header).
__global__ __launch_bounds__(256) void conv2_kernel(
    const float* __restrict__ in, const float* __restrict__ wT,
    const float* __restrict__ bias, float* __restrict__ out) {
#pragma clang fp contract(off)
    __shared__ __align__(16) float Wl[2][8][16][32];  // double-buffered
    __shared__ __align__(16) float Il[8][4][68];      // [cl][row][col<=66]
    const int tid = threadIdx.x;
    const int xg = tid & 15, cog = tid >> 4;
    const int xt = blockIdx.x & 3, cot = blockIdx.x >> 2;
    const int oy = blockIdx.y;
    const int img = blockIdx.z;
    const int xbase = 32 * xt;
    const float* inp = in + (size_t)img * 4194304;
    const int gx0 = 2 * xbase - 1;
    const int iy0 = 2 * oy - 1;
    const int lane = tid & 63, wid = tid >> 6;

    // --- staging descriptors, computed once (leaf-invariant) ---
    int ldsoff[9]; int goff[9]; bool gok[9];
#pragma unroll
    for (int i = 0; i < 9; ++i) {
        int e = tid + i * 256;
        int cl = e / 264;
        int rem = e - cl * 264;
        int row = rem / 66, col = rem - row * 66;
        int iy = iy0 + row, gx = gx0 + col;
        gok[i] = (e < 2112) && ((unsigned)iy < 256u) && ((unsigned)gx < 256u);
        ldsoff[i] = (cl * 4 + row) * 68 + col;
        goff[i] = cl * 65536 + iy * 256 + gx;
    }
    const float* wbase = wT + cot * 32;

    float rIl[9];
    auto LOAD_IL = [&](int L) {                 // issue global->reg loads
        const float* p = inp + (size_t)L * 524288;  // 8ci * 65536
#pragma unroll
        for (int i = 0; i < 9; ++i)
            rIl[i] = gok[i] ? p[goff[i]] : 0.f;
    };

    float r[8][2][2];
    float ls[8][2][2];
#pragma unroll
    for (int j = 0; j < 8; ++j)
#pragma unroll
        for (int c = 0; c < 2; ++c) { r[j][c][0] = r[j][c][1] = 0.f; }

    // prime leaf 0
    stage_w8(wbase, &Wl[0][0][0][0], wid, lane);
    LOAD_IL(0);

    int buf = 0;
    for (int L = 0; L < 8; ++L) {
        // write staged inputs (loads issued one full leaf ago)
#pragma unroll
        for (int i = 0; i < 8; ++i) ((float*)Il)[ldsoff[i]] = rIl[i];
        if (tid < 64) ((float*)Il)[ldsoff[8]] = rIl[8];
        __syncthreads();   // Il + Wl[buf] visible (vmcnt drained at barrier)

        if (L < 7) {       // prefetch leaf L+1 under this leaf's compute
            stage_w8(wbase + (size_t)(L + 1) * 16384, &Wl[buf ^ 1][0][0][0],
                     wid, lane);
            LOAD_IL(L + 1);
        }

        for (int cl = 0; cl < 8; ++cl) {
            float rin[4][6];
#pragma unroll
            for (int ky = 0; ky < 4; ++ky) {
                float4 v4 = *(const float4*)&Il[cl][ky][4 * xg];
                float2 v2 = *(const float2*)&Il[cl][ky][4 * xg + 4];
                rin[ky][0] = v4.x; rin[ky][1] = v4.y; rin[ky][2] = v4.z;
                rin[ky][3] = v4.w; rin[ky][4] = v2.x; rin[ky][5] = v2.y;
            }
            float wv[2][16];
#pragma unroll
            for (int f = 0; f < 16; ++f) {
                float2 wp = *(const float2*)&Wl[buf][cl][f][cog * 2];
                wv[0][f] = wp.x; wv[1][f] = wp.y;
            }
#pragma unroll
            for (int j = 0; j < 8; ++j) {
                int ky1 = j >> 2, kx1 = j & 3;
                int ky2 = 2 + ky1, kx2 = kx1;
#pragma unroll
                for (int c = 0; c < 2; ++c)
#pragma unroll
                    for (int xi = 0; xi < 2; ++xi) {
                        float p1 = rin[ky1][2 * xi + kx1] * wv[c][j];
                        r[j][c][xi] = r[j][c][xi] + p1;
                        float p2 = rin[ky2][2 * xi + kx2] * wv[c][j + 8];
                        r[j][c][xi] = r[j][c][xi] + p2;
                    }
            }
        }

        // leaf combine + reset (identical tree to R12)
#pragma unroll
        for (int c = 0; c < 2; ++c)
#pragma unroll
            for (int xi = 0; xi < 2; ++xi) {
                float t01 = r[0][c][xi] + r[1][c][xi];
                float t23 = r[2][c][xi] + r[3][c][xi];
                float t45 = r[4][c][xi] + r[5][c][xi];
                float t67 = r[6][c][xi] + r[7][c][xi];
                ls[L][c][xi] = (t01 + t23) + (t45 + t67);
            }
#pragma unroll
        for (int j = 0; j < 8; ++j)
#pragma unroll
            for (int c = 0; c < 2; ++c) { r[j][c][0] = 0.f; r[j][c][1] = 0.f; }

        __syncthreads();   // all readers of Il / Wl[buf] done
        buf ^= 1;
    }

#pragma unroll
    for (int c = 0; c < 2; ++c) {
        int co = cot * 32 + cog * 2 + c;
        float bv = bias[co];
        float res[2];
#pragma unroll
        for (int xi = 0; xi < 2; ++xi) {
            float t01 = ls[0][c][xi] + ls[1][c][xi];
            float t23 = ls[2][c][xi] + ls[3][c][xi];
            float t45 = ls[4][c][xi] + ls[5][c][xi];
            float t67 = ls[6][c][xi] + ls[7][c][xi];
            float tot = (t01 + t23) + (t45 + t67);
            res[xi] = fmaxf(tot + bv, 0.f);
        }
        float2 v; v.x = res[0]; v.y = res[1];
        *(float2*)&out[(size_t)img * 2097152 + (size_t)co * 16384 +
                       (size_t)oy * 128 + xbase + 2 * xg] = v;
    }
}

// ---------------- conv3: 128->128, 4x4, s2, p1, 128->64. K=2048, 16 leaves
// as two 8-leaf halves (A+B). Same async restructure as conv2.
__global__ __launch_bounds__(256) void conv3_kernel(
    const float* __restrict__ in, const float* __restrict__ wT,
    const float* __restrict__ bias, float* __restrict__ out) {
#pragma clang fp contract(off)
    __shared__ __align__(16) float Wl[2][8][16][32];
    __shared__ __align__(16) float Il[8][4][68];
    const int tid = threadIdx.x;
    const int xg = tid & 15, cog = tid >> 4;
    const int xt = blockIdx.x & 1, cot = blockIdx.x >> 1;
    const int oy = blockIdx.y;
    const int img = blockIdx.z;
    const int xbase = 32 * xt;
    const float* inp = in + (size_t)img * 2097152;
    const int gx0 = 2 * xbase - 1;
    const int iy0 = 2 * oy - 1;
    const int lane = tid & 63, wid = tid >> 6;

    int ldsoff[9]; int goff[9]; bool gok[9];
#pragma unroll
    for (int i = 0; i < 9; ++i) {
        int e = tid + i * 256;
        int cl = e / 264;
        int rem = e - cl * 264;
        int row = rem / 66, col = rem - row * 66;
        int iy = iy0 + row, gx = gx0 + col;
        gok[i] = (e < 2112) && ((unsigned)iy < 128u) && ((unsigned)gx < 128u);
        ldsoff[i] = (cl * 4 + row) * 68 + col;
        goff[i] = cl * 16384 + iy * 128 + gx;
    }
    const float* wbase = wT + cot * 32;

    float rIl[9];
    auto LOAD_IL = [&](int L) {
        const float* p = inp + (size_t)L * 131072;  // 8ci * 16384
#pragma unroll
        for (int i = 0; i < 9; ++i)
            rIl[i] = gok[i] ? p[goff[i]] : 0.f;
    };

    float r[8][2][2];
    float ls[8][2][2];
    float AB[2][2][2];
#pragma unroll
    for (int j = 0; j < 8; ++j)
#pragma unroll
        for (int c = 0; c < 2; ++c) { r[j][c][0] = r[j][c][1] = 0.f; }

    stage_w8(wbase, &Wl[0][0][0][0], wid, lane);
    LOAD_IL(0);

    int buf = 0;
    for (int half = 0; half < 2; ++half) {
        for (int L8 = 0; L8 < 8; ++L8) {
            int L = half * 8 + L8;
#pragma unroll
            for (int i = 0; i < 8; ++i) ((float*)Il)[ldsoff[i]] = rIl[i];
            if (tid < 64) ((float*)Il)[ldsoff[8]] = rIl[8];
            __syncthreads();

            if (L < 15) {
                stage_w8(wbase + (size_t)(L + 1) * 16384,
                         &Wl[buf ^ 1][0][0][0], wid, lane);
                LOAD_IL(L + 1);
            }

            for (int cl = 0; cl < 8; ++cl) {
                float rin[4][6];
#pragma unroll
                for (int ky = 0; ky < 4; ++ky) {
                    float4 v4 = *(const float4*)&Il[cl][ky][4 * xg];
                    float2 v2 = *(const float2*)&Il[cl][ky][4 * xg + 4];
                    rin[ky][0] = v4.x; rin[ky][1] = v4.y; rin[ky][2] = v4.z;
                    rin[ky][3] = v4.w; rin[ky][4] = v2.x; rin[ky][5] = v2.y;
                }
                float wv[2][16];
#pragma unroll
                for (int f = 0; f < 16; ++f) {
                    float2 wp = *(const float2*)&Wl[buf][cl][f][cog * 2];
                    wv[0][f] = wp.x; wv[1][f] = wp.y;
                }
#pragma unroll
                for (int j = 0; j < 8; ++j) {
                    int ky1 = j >> 2, kx1 = j & 3;
                    int ky2 = 2 + ky1, kx2 = kx1;
#pragma unroll
                    for (int c = 0; c < 2; ++c)
#pragma unroll
                        for (int xi = 0; xi < 2; ++xi) {
                            float p1 = rin[ky1][2 * xi + kx1] * wv[c][j];
                            r[j][c][xi] = r[j][c][xi] + p1;
                            float p2 = rin[ky2][2 * xi + kx2] * wv[c][j + 8];
                            r[j][c][xi] = r[j][c][xi] + p2;
                        }
                }
            }

#pragma unroll
            for (int c = 0; c < 2; ++c)
#pragma unroll
                for (int xi = 0; xi < 2; ++xi) {
                    float t01 = r[0][c][xi] + r[1][c][xi];
                    float t23 = r[2][c][xi] + r[3][c][xi];
                    float t45 = r[4][c][xi] + r[5][c][xi];
                    float t67 = r[6][c][xi] + r[7][c][xi];
                    ls[L8][c][xi] = (t01 + t23) + (t45 + t67);
                }
#pragma unroll
            for (int j = 0; j < 8; ++j)
#pragma unroll
                for (int c = 0; c < 2; ++c) { r[j][c][0] = 0.f; r[j][c][1] = 0.f; }

            __syncthreads();
            buf ^= 1;
        }
        // half combine: p(1024) over these 8 leaves
#pragma unroll
        for (int c = 0; c < 2; ++c)
#pragma unroll
            for (int xi = 0; xi < 2; ++xi) {
                float t01 = ls[0][c][xi] + ls[1][c][xi];
                float t23 = ls[2][c][xi] + ls[3][c][xi];
                float t45 = ls[4][c][xi] + ls[5][c][xi];
                float t67 = ls[6][c][xi] + ls[7][c][xi];
                AB[half][c][xi] = (t01 + t23) + (t45 + t67);
            }
    }

#pragma unroll
    for (int c = 0; c < 2; ++c) {
        int co = cot * 32 + cog * 2 + c;
        float bv = bias[co];
        float res[2];
#pragma unroll
        for (int xi = 0; xi < 2; ++xi) {
            float tot = AB[0][c][xi] + AB[1][c][xi];   // p(2048)
            res[xi] = fmaxf(tot + bv, 0.f);
        }
        float2 v; v.x = res[0]; v.y = res[1];
        *(float2*)&out[(size_t)img * 524288 + (size_t)co * 4096 +
                       (size_t)oy * 64 + xbase + 2 * xg] = v;
    }
}

// ---------------- conv4: 128->4, 3x3, s1, p1 (unchanged from R12)
__global__ __launch_bounds__(256) void conv4_kernel(
    const float* __restrict__ h3, const float* __restrict__ w4,
    const float* __restrict__ b4, float* __restrict__ z, int b0) {
#pragma clang fp contract(off)
    __shared__ __align__(16) float Il3[8][3][66];
    __shared__ __align__(16) float w4l[4608];
    const int tid = threadIdx.x;
    const int wl = tid & 63, co = tid >> 6;
    const int h = blockIdx.x, bl = blockIdx.y;
    const float* inp = h3 + (size_t)bl * 524288;

    for (int it = 0; it < 18; ++it) {
        int e = tid + it * 256;
        if (e < 4608) w4l[e] = w4[e];
    }

    float ls[16];
    for (int L = 0; L < 16; ++L) {
        __syncthreads();
        for (int it = 0; it < 7; ++it) {
            int e = tid + it * 256;
            if (e < 1584) {
                int cil = e / 198;
                int rem = e - cil * 198;
                int ky = rem / 66, col = rem - ky * 66;
                int iy = h - 1 + ky, gx = col - 1;
                bool ok = ((unsigned)iy < 64u) && ((unsigned)gx < 64u);
                Il3[cil][ky][col] =
                    ok ? inp[(size_t)(8 * L + cil) * 4096 + iy * 64 + gx] : 0.f;
            }
        }
        __syncthreads();

        float r[8];
#pragma unroll
        for (int j = 0; j < 8; ++j) r[j] = 0.f;
#pragma unroll
        for (int i = 0; i < 9; ++i) {
#pragma unroll
            for (int j = 0; j < 8; ++j) {
                int kk = 8 * i + j;
                int cil = kk / 9, f = kk - 9 * cil;
                int ky = f / 3, kx = f - 3 * ky;
                float p = Il3[cil][ky][wl + kx] *
                          w4l[co * 1152 + (8 * L + cil) * 9 + f];
                r[j] = r[j] + p;
            }
        }
        float t01 = r[0] + r[1], t23 = r[2] + r[3];
        float t45 = r[4] + r[5], t67 = r[6] + r[7];
        ls[L] = (t01 + t23) + (t45 + t67);
    }

    float a01 = ls[0] + ls[1],  a23 = ls[2] + ls[3];
    float a45 = ls[4] + ls[5],  a67 = ls[6] + ls[7];
    float A = (a01 + a23) + (a45 + a67);
    float c01 = ls[8] + ls[9],  c23 = ls[10] + ls[11];
    float c45 = ls[12] + ls[13], c67 = ls[14] + ls[15];
    float B = (c01 + c23) + (c45 + c67);
    float tot = A + B;

    z[(size_t)(b0 + bl) * 16384 + (size_t)co * 4096 + (size_t)h * 64 + wl] =
        tot + b4[co];
}

// ---------------- VQ (unchanged from R12)
__global__ __launch_bounds__(256) void vq_kernel(
    const float* __restrict__ z, const float* __restrict__ emb,
    float* __restrict__ zq_out, float* __restrict__ idx_out,
    float* __restrict__ loss_out) {
#pragma clang fp contract(off)
    __shared__ float4 el[512];
    __shared__ float t3s[512];
    const int tid = threadIdx.x;
#pragma unroll
    for (int i = 0; i < 2; ++i) {
        int e = tid + i * 256;
        float4 v = ((const float4*)emb)[e];
        el[e] = v;
        float q0 = v.x * v.x, q1 = v.y * v.y, q2 = v.z * v.z, q3 = v.w * v.w;
        t3s[e] = ((q0 + q1) + q2) + q3;
    }
    __syncthreads();

    const int r = blockIdx.x * 256 + tid;
    float4 v = ((const float4*)z)[r];
    float q0 = v.x * v.x, q1 = v.y * v.y, q2 = v.z * v.z, q3 = v.w * v.w;
    float t1 = ((q0 + q1) + q2) + q3;

    float best = __builtin_inff();
    int bi = 0;
    for (int jj = 0; jj < 512; ++jj) {
        float4 e = el[jj];
        float t2 = fmaf(v.x, e.x, 0.f);
        t2 = fmaf(v.y, e.y, t2);
        t2 = fmaf(v.z, e.z, t2);
        t2 = fmaf(v.w, e.w, t2);
        float two_t2 = 2.f * t2;
        float d = (t1 - two_t2) + t3s[jj];
        if (d < best) { best = d; bi = jj; }
    }
    float4 q = el[bi];
    ((float4*)zq_out)[r] = q;
    idx_out[r] = (float)bi;

    double dx = (double)q.x - v.x, dy = (double)q.y - v.y;
    double dz2 = (double)q.z - v.z, dw = (double)q.w - v.w;
    double part = dx * dx + dy * dy + dz2 * dz2 + dw * dw;
#pragma unroll
    for (int off = 32; off > 0; off >>= 1) part += __shfl_down(part, off, 64);
    __shared__ double ps[4];
    if ((tid & 63) == 0) ps[tid >> 6] = part;
    __syncthreads();
    if (tid == 0) {
        double s = ps[0] + ps[1] + ps[2] + ps[3];
        atomicAdd(loss_out, (float)(s * (1.25 / 262144.0)));
    }
}

// ---------------------------------------------------------------------------
extern "C" void kernel_launch(void* const* d_in, const int* in_sizes, int n_in,
                              void* d_out, int out_size, void* d_ws, size_t ws_size,
                              hipStream_t stream) {
    const float* x   = (const float*)d_in[0];
    const float* w1  = (const float*)d_in[1];
    const float* b1  = (const float*)d_in[2];
    const float* w2  = (const float*)d_in[3];
    const float* b2  = (const float*)d_in[4];
    const float* w3  = (const float*)d_in[5];
    const float* b3  = (const float*)d_in[6];
    const float* w4  = (const float*)d_in[7];
    const float* b4  = (const float*)d_in[8];
    const float* emb = (const float*)d_in[9];
    float* out = (float*)d_out;

    float* ws = (float*)d_ws;
    // layout (floats): zb[262144] | wT2[131072] | wT3[262144]
    //                 | h1c[CH*4194304] | h2c[CH*2097152] | h3c[CH*524288]
    int CH = 4;
    while (CH > 1 &&
           ((size_t)655360u + (size_t)CH * 6815744u) * 4ull > ws_size)
        CH >>= 1;
    float* zb  = ws;
    float* wT2 = ws + 262144;
    float* wT3 = wT2 + 131072;
    float* h1c = wT3 + 262144;
    float* h2c = h1c + (size_t)CH * 4194304;
    float* h3c = h2c + (size_t)CH * 2097152;

    wt_kernel<<<1536, 256, 0, stream>>>(w2, w3, wT2, wT3);

    for (int b0 = 0; b0 < 16; b0 += CH) {
        conv1_kernel<<<dim3(4, 16, CH), 256, 0, stream>>>(
            x + (size_t)b0 * 262144, w1, b1, h1c);
        conv2_kernel<<<dim3(16, 128, CH), 256, 0, stream>>>(h1c, wT2, b2, h2c);
        conv3_kernel<<<dim3(8, 64, CH), 256, 0, stream>>>(h2c, wT3, b3, h3c);
        conv4_kernel<<<dim3(64, CH), 256, 0, stream>>>(h3c, w4, b4, zb, b0);
    }

    hipMemsetAsync(out + 262144, 0, sizeof(float), stream);  // loss accumulator
    vq_kernel<<<256, 256, 0, stream>>>(zb, emb, out, out + 262144 + 1, out + 262144);
}

// Round 2
// 3260.270 us; speedup vs baseline: 1.8712x; 1.1006x over previous
//
#include <hip/hip_runtime.h>

// ---------------------------------------------------------------------------
// VQ-VAE encoder — numpy-pairwise fp32 emulation (R12 semantics, PASSING).
// R15: packed-fp32 restructure of conv2/conv3 MAC loops + single barrier/leaf.
// Bit-exactness invariant: identical products, identical per-accumulator op
// order, identical tree. v_pk_mul_f32/v_pk_add_f32 are 2x independent IEEE
// fp32 ops (same rounding as v_mul/v_add); accumulators packed over the two
// co outputs (c=0,1); weight pair {w[co0],w[co1]} is the existing contiguous
// float2 in Wl; input scalar broadcast via VOP3P op_sel (no extra movs).
// Il now double-buffered like Wl -> ONE __syncthreads per leaf (was 2).
// conv1/conv4/vq unchanged from R12.
// d_out: z_q_st[262144] | loss[1] | idx[65536]
// ---------------------------------------------------------------------------

#define TREE8(r) ((((r)[0]+(r)[1])+((r)[2]+(r)[3]))+((((r)[4]+(r)[5]))+((r)[6]+(r)[7])))

typedef __attribute__((__ext_vector_type__(2))) float v2f;

// d = {a.lo*w.lo, a.lo*w.hi}  (broadcast low dword of a)
__device__ __forceinline__ v2f pk_mul_lo(v2f a, v2f w) {
    v2f d;
    asm("v_pk_mul_f32 %0, %1, %2 op_sel:[0,0] op_sel_hi:[0,1]"
        : "=v"(d) : "v"(a), "v"(w));
    return d;
}
// d = {a.hi*w.lo, a.hi*w.hi}  (broadcast high dword of a)
__device__ __forceinline__ v2f pk_mul_hi(v2f a, v2f w) {
    v2f d;
    asm("v_pk_mul_f32 %0, %1, %2 op_sel:[1,0] op_sel_hi:[1,1]"
        : "=v"(d) : "v"(a), "v"(w));
    return d;
}
// r += p (per-half IEEE add, in place)
__device__ __forceinline__ void pk_acc(v2f& r, v2f p) {
    asm("v_pk_add_f32 %0, %0, %1" : "+v"(r) : "v"(p));
}
// d = a + b (per-half IEEE add)
__device__ __forceinline__ v2f pk_add2(v2f a, v2f b) {
    v2f d;
    asm("v_pk_add_f32 %0, %1, %2" : "=v"(d) : "v"(a), "v"(b));
    return d;
}

// async global->LDS for one 8ci weight leaf: 4096 floats, 16 chunks of 256.
// wave w issues chunks w*4..w*4+3; lane l covers floats 4l..4l+3 of chunk.
// LDS linear idx e <-> (cl=e>>9, f=(e>>5)&15, co=e&31); src co-contiguous.
__device__ __forceinline__ void stage_w8(const float* __restrict__ src0,
                                         float* dst0, int wid, int lane) {
#pragma unroll
    for (int it = 0; it < 4; ++it) {
        int j = wid * 4 + it;
        int e = j * 256 + lane * 4;
        int co = e & 31, f = (e >> 5) & 15, cl = e >> 9;
        const float* src = src0 + cl * 2048 + f * 128 + co;
        __builtin_amdgcn_global_load_lds(
            (const __attribute__((address_space(1))) void*)src,
            (__attribute__((address_space(3))) void*)(dst0 + j * 256),
            16, 0, 0);
    }
}

// ---------------- weight transform: wT[ci][f][co] from w[co][ci][f]
__global__ __launch_bounds__(256) void wt_kernel(
    const float* __restrict__ w2, const float* __restrict__ w3,
    float* __restrict__ wT2, float* __restrict__ wT3) {
    int g = blockIdx.x * 256 + threadIdx.x;
    if (g < 131072) {             // conv2: ci 64, f 16, co 128
        int co = g & 127, f = (g >> 7) & 15, ci = g >> 11;
        wT2[g] = w2[co * 1024 + ci * 16 + f];
    }
    int g2 = g - 131072;
    if (g2 >= 0 && g2 < 262144) { // conv3: ci 128, f 16, co 128
        int co = g2 & 127, f = (g2 >> 7) & 15, ci = g2 >> 11;
        wT3[g2] = w3[co * 2048 + ci * 16 + f];
    }
}

// ---------------- conv1: 1->64, 4x4, s2, p1 (unchanged from R12)
__global__ __launch_bounds__(256) void conv1_kernel(
    const float* __restrict__ x, const float* __restrict__ w1,
    const float* __restrict__ b1, float* __restrict__ h1) {
#pragma clang fp contract(off)
    __shared__ __align__(16) float wl[64 * 16];
    __shared__ float bl[64];
    const int tid = threadIdx.x;
    {
        const float4* src = (const float4*)w1;
        ((float4*)wl)[tid] = src[tid];
        if (tid < 64) bl[tid] = b1[tid];
    }
    __syncthreads();

    const int oxl = tid & 63, oyq = tid >> 6;
    const int img = blockIdx.z;
    const int ox  = blockIdx.x * 64 + oxl;
    const int oy0 = blockIdx.y * 16 + oyq * 4;
    const float* xi = x + (size_t)img * 262144;

    float in[10][4];
    const int ix0 = 2 * ox - 1;
    const int iy0 = 2 * oy0 - 1;
#pragma unroll
    for (int r = 0; r < 10; ++r) {
        int iy = iy0 + r;
#pragma unroll
        for (int k = 0; k < 4; ++k) {
            int ixx = ix0 + k;
            bool ok = ((unsigned)iy < 512u) && ((unsigned)ixx < 512u);
            in[r][k] = ok ? xi[iy * 512 + ixx] : 0.f;
        }
    }

    float* outp = h1 + (size_t)img * 4194304;
#pragma unroll
    for (int c = 0; c < 64; ++c) {
        const float* wp = &wl[c * 16];
        float bv = bl[c];
#pragma unroll
        for (int p = 0; p < 4; ++p) {
            float a[16];
#pragma unroll
            for (int f = 0; f < 16; ++f)
                a[f] = in[2 * p + (f >> 2)][f & 3] * wp[f];
            float r[8];
#pragma unroll
            for (int j = 0; j < 8; ++j) r[j] = a[j] + a[8 + j];
            float tot = TREE8(r);
            outp[(size_t)c * 65536 + (size_t)(oy0 + p) * 256 + ox] =
                fmaxf(tot + bv, 0.f);
        }
    }
}

// ---------------- conv2: 64->128, 4x4, s2, p1, 256->128. K=1024, 8 leaves.
// tile 32ox x 32co x 1oy; packed fp32 over co-pair; dbuf Il+Wl, 1 barrier/leaf.
__global__ __launch_bounds__(256) void conv2_kernel(
    const float* __restrict__ in, const float* __restrict__ wT,
    const float* __restrict__ bias, float* __restrict__ out) {
#pragma clang fp contract(off)
    __shared__ __align__(16) float Wl[2][8][16][32];  // [buf][cl][f][co]
    __shared__ __align__(16) float Il[2][8][4][68];   // [buf][cl][row][col<=66]
    const int tid = threadIdx.x;
    const int xg = tid & 15, cog = tid >> 4;
    const int xt = blockIdx.x & 3, cot = blockIdx.x >> 2;
    const int oy = blockIdx.y;
    const int img = blockIdx.z;
    const int xbase = 32 * xt;
    const float* inp = in + (size_t)img * 4194304;
    const int gx0 = 2 * xbase - 1;
    const int iy0 = 2 * oy - 1;
    const int lane = tid & 63, wid = tid >> 6;

    // --- staging descriptors, computed once (leaf-invariant) ---
    int ldsoff[9]; int goff[9]; bool gok[9];
#pragma unroll
    for (int i = 0; i < 9; ++i) {
        int e = tid + i * 256;
        int cl = e / 264;
        int rem = e - cl * 264;
        int row = rem / 66, col = rem - row * 66;
        int iy = iy0 + row, gx = gx0 + col;
        gok[i] = (e < 2112) && ((unsigned)iy < 256u) && ((unsigned)gx < 256u);
        ldsoff[i] = (cl * 4 + row) * 68 + col;
        goff[i] = cl * 65536 + iy * 256 + gx;
    }
    const float* wbase = wT + cot * 32;

    float rIl[9];
    auto LOAD_IL = [&](int L) {                 // issue global->reg loads
        const float* p = inp + (size_t)L * 524288;  // 8ci * 65536
#pragma unroll
        for (int i = 0; i < 9; ++i)
            rIl[i] = gok[i] ? p[goff[i]] : 0.f;
    };

    v2f r[8][2];    // [j][xi], packed over co-pair (c=0,1)
    v2f ls[8][2];   // [leaf][xi]
#pragma unroll
    for (int j = 0; j < 8; ++j)
#pragma unroll
        for (int xi = 0; xi < 2; ++xi) r[j][xi] = (v2f){0.f, 0.f};

    // prologue: prime leaf 0 (Il[0], Wl[0]) and issue leaf-1 loads
    stage_w8(wbase, &Wl[0][0][0][0], wid, lane);
    LOAD_IL(0);
    {
        float* Il0 = &Il[0][0][0][0];
#pragma unroll
        for (int i = 0; i < 8; ++i) Il0[ldsoff[i]] = rIl[i];
        if (tid < 64) Il0[ldsoff[8]] = rIl[8];
    }
    LOAD_IL(1);
    __syncthreads();

    int buf = 0;
    for (int L = 0; L < 8; ++L) {
        // stage leaf L+1 into the other buffer (rIl holds its data)
        if (L < 7) {
            float* Iln = &Il[buf ^ 1][0][0][0];
#pragma unroll
            for (int i = 0; i < 8; ++i) Iln[ldsoff[i]] = rIl[i];
            if (tid < 64) Iln[ldsoff[8]] = rIl[8];
            stage_w8(wbase + (size_t)(L + 1) * 16384, &Wl[buf ^ 1][0][0][0],
                     wid, lane);
        }
        if (L < 6) LOAD_IL(L + 2);

        const float* IlC = &Il[buf][0][0][0];
        const float* WlC = &Wl[buf][0][0][0];
        for (int cl = 0; cl < 8; ++cl) {
            v2f rp[4][3];
#pragma unroll
            for (int ky = 0; ky < 4; ++ky) {
                const float* row = IlC + (cl * 4 + ky) * 68 + 4 * xg;
                rp[ky][0] = *(const v2f*)(row);
                rp[ky][1] = *(const v2f*)(row + 2);
                rp[ky][2] = *(const v2f*)(row + 4);
            }
            v2f wp[16];
#pragma unroll
            for (int f = 0; f < 16; ++f)
                wp[f] = *(const v2f*)(WlC + (cl * 16 + f) * 32 + cog * 2);
#pragma unroll
            for (int j = 0; j < 8; ++j) {
                const int ky1 = j >> 2, kx1 = j & 3;
#pragma unroll
                for (int xi = 0; xi < 2; ++xi) {
                    const int e = 2 * xi + kx1;       // 0..5
                    v2f p1 = (e & 1) ? pk_mul_hi(rp[ky1][e >> 1], wp[j])
                                     : pk_mul_lo(rp[ky1][e >> 1], wp[j]);
                    pk_acc(r[j][xi], p1);
                    v2f p2 = (e & 1) ? pk_mul_hi(rp[2 + ky1][e >> 1], wp[j + 8])
                                     : pk_mul_lo(rp[2 + ky1][e >> 1], wp[j + 8]);
                    pk_acc(r[j][xi], p2);
                }
            }
        }

        // leaf combine + reset (identical tree per half to R12's per-c tree)
#pragma unroll
        for (int xi = 0; xi < 2; ++xi) {
            v2f t01 = pk_add2(r[0][xi], r[1][xi]);
            v2f t23 = pk_add2(r[2][xi], r[3][xi]);
            v2f t45 = pk_add2(r[4][xi], r[5][xi]);
            v2f t67 = pk_add2(r[6][xi], r[7][xi]);
            ls[L][xi] = pk_add2(pk_add2(t01, t23), pk_add2(t45, t67));
        }
#pragma unroll
        for (int j = 0; j < 8; ++j)
#pragma unroll
            for (int xi = 0; xi < 2; ++xi) r[j][xi] = (v2f){0.f, 0.f};

        __syncthreads();   // leaf L readers done; leaf L+1 buffers complete
        buf ^= 1;
    }

    {
        v2f bvp = *(const v2f*)(bias + cot * 32 + cog * 2);
        v2f T[2];
#pragma unroll
        for (int xi = 0; xi < 2; ++xi) {
            v2f u01 = pk_add2(ls[0][xi], ls[1][xi]);
            v2f u23 = pk_add2(ls[2][xi], ls[3][xi]);
            v2f u45 = pk_add2(ls[4][xi], ls[5][xi]);
            v2f u67 = pk_add2(ls[6][xi], ls[7][xi]);
            v2f tot = pk_add2(pk_add2(u01, u23), pk_add2(u45, u67));
            T[xi] = pk_add2(tot, bvp);          // +bias per co half
        }
        const int co0 = cot * 32 + cog * 2;
        float r00 = fmaxf(T[0].x, 0.f), r01 = fmaxf(T[1].x, 0.f);
        float r10 = fmaxf(T[0].y, 0.f), r11 = fmaxf(T[1].y, 0.f);
        v2f o0; o0.x = r00; o0.y = r01;
        v2f o1; o1.x = r10; o1.y = r11;
        size_t base = (size_t)img * 2097152 + (size_t)oy * 128 + xbase + 2 * xg;
        *(v2f*)&out[base + (size_t)co0 * 16384] = o0;
        *(v2f*)&out[base + (size_t)(co0 + 1) * 16384] = o1;
    }
}

// ---------------- conv3: 128->128, 4x4, s2, p1, 128->64. K=2048, 16 leaves
// as two 8-leaf halves (A+B). Same packed restructure as conv2.
__global__ __launch_bounds__(256) void conv3_kernel(
    const float* __restrict__ in, const float* __restrict__ wT,
    const float* __restrict__ bias, float* __restrict__ out) {
#pragma clang fp contract(off)
    __shared__ __align__(16) float Wl[2][8][16][32];
    __shared__ __align__(16) float Il[2][8][4][68];
    const int tid = threadIdx.x;
    const int xg = tid & 15, cog = tid >> 4;
    const int xt = blockIdx.x & 1, cot = blockIdx.x >> 1;
    const int oy = blockIdx.y;
    const int img = blockIdx.z;
    const int xbase = 32 * xt;
    const float* inp = in + (size_t)img * 2097152;
    const int gx0 = 2 * xbase - 1;
    const int iy0 = 2 * oy - 1;
    const int lane = tid & 63, wid = tid >> 6;

    int ldsoff[9]; int goff[9]; bool gok[9];
#pragma unroll
    for (int i = 0; i < 9; ++i) {
        int e = tid + i * 256;
        int cl = e / 264;
        int rem = e - cl * 264;
        int row = rem / 66, col = rem - row * 66;
        int iy = iy0 + row, gx = gx0 + col;
        gok[i] = (e < 2112) && ((unsigned)iy < 128u) && ((unsigned)gx < 128u);
        ldsoff[i] = (cl * 4 + row) * 68 + col;
        goff[i] = cl * 16384 + iy * 128 + gx;
    }
    const float* wbase = wT + cot * 32;

    float rIl[9];
    auto LOAD_IL = [&](int L) {
        const float* p = inp + (size_t)L * 131072;  // 8ci * 16384
#pragma unroll
        for (int i = 0; i < 9; ++i)
            rIl[i] = gok[i] ? p[goff[i]] : 0.f;
    };

    v2f r[8][2];
    v2f ls[8][2];
    v2f AB[2][2];
#pragma unroll
    for (int j = 0; j < 8; ++j)
#pragma unroll
        for (int xi = 0; xi < 2; ++xi) r[j][xi] = (v2f){0.f, 0.f};

    stage_w8(wbase, &Wl[0][0][0][0], wid, lane);
    LOAD_IL(0);
    {
        float* Il0 = &Il[0][0][0][0];
#pragma unroll
        for (int i = 0; i < 8; ++i) Il0[ldsoff[i]] = rIl[i];
        if (tid < 64) Il0[ldsoff[8]] = rIl[8];
    }
    LOAD_IL(1);
    __syncthreads();

    int buf = 0;
    for (int half = 0; half < 2; ++half) {
        for (int L8 = 0; L8 < 8; ++L8) {
            const int L = half * 8 + L8;
            if (L < 15) {
                float* Iln = &Il[buf ^ 1][0][0][0];
#pragma unroll
                for (int i = 0; i < 8; ++i) Iln[ldsoff[i]] = rIl[i];
                if (tid < 64) Iln[ldsoff[8]] = rIl[8];
                stage_w8(wbase + (size_t)(L + 1) * 16384,
                         &Wl[buf ^ 1][0][0][0], wid, lane);
            }
            if (L < 14) LOAD_IL(L + 2);

            const float* IlC = &Il[buf][0][0][0];
            const float* WlC = &Wl[buf][0][0][0];
            for (int cl = 0; cl < 8; ++cl) {
                v2f rp[4][3];
#pragma unroll
                for (int ky = 0; ky < 4; ++ky) {
                    const float* row = IlC + (cl * 4 + ky) * 68 + 4 * xg;
                    rp[ky][0] = *(const v2f*)(row);
                    rp[ky][1] = *(const v2f*)(row + 2);
                    rp[ky][2] = *(const v2f*)(row + 4);
                }
                v2f wp[16];
#pragma unroll
                for (int f = 0; f < 16; ++f)
                    wp[f] = *(const v2f*)(WlC + (cl * 16 + f) * 32 + cog * 2);
#pragma unroll
                for (int j = 0; j < 8; ++j) {
                    const int ky1 = j >> 2, kx1 = j & 3;
#pragma unroll
                    for (int xi = 0; xi < 2; ++xi) {
                        const int e = 2 * xi + kx1;
                        v2f p1 = (e & 1) ? pk_mul_hi(rp[ky1][e >> 1], wp[j])
                                         : pk_mul_lo(rp[ky1][e >> 1], wp[j]);
                        pk_acc(r[j][xi], p1);
                        v2f p2 = (e & 1) ? pk_mul_hi(rp[2 + ky1][e >> 1], wp[j + 8])
                                         : pk_mul_lo(rp[2 + ky1][e >> 1], wp[j + 8]);
                        pk_acc(r[j][xi], p2);
                    }
                }
            }

#pragma unroll
            for (int xi = 0; xi < 2; ++xi) {
                v2f t01 = pk_add2(r[0][xi], r[1][xi]);
                v2f t23 = pk_add2(r[2][xi], r[3][xi]);
                v2f t45 = pk_add2(r[4][xi], r[5][xi]);
                v2f t67 = pk_add2(r[6][xi], r[7][xi]);
                ls[L8][xi] = pk_add2(pk_add2(t01, t23), pk_add2(t45, t67));
            }
#pragma unroll
            for (int j = 0; j < 8; ++j)
#pragma unroll
                for (int xi = 0; xi < 2; ++xi) r[j][xi] = (v2f){0.f, 0.f};

            __syncthreads();
            buf ^= 1;
        }
        // half combine: p(1024) over these 8 leaves
#pragma unroll
        for (int xi = 0; xi < 2; ++xi) {
            v2f t01 = pk_add2(ls[0][xi], ls[1][xi]);
            v2f t23 = pk_add2(ls[2][xi], ls[3][xi]);
            v2f t45 = pk_add2(ls[4][xi], ls[5][xi]);
            v2f t67 = pk_add2(ls[6][xi], ls[7][xi]);
            AB[half][xi] = pk_add2(pk_add2(t01, t23), pk_add2(t45, t67));
        }
    }

    {
        v2f bvp = *(const v2f*)(bias + cot * 32 + cog * 2);
        v2f T[2];
#pragma unroll
        for (int xi = 0; xi < 2; ++xi) {
            v2f tot = pk_add2(AB[0][xi], AB[1][xi]);   // p(2048)
            T[xi] = pk_add2(tot, bvp);
        }
        const int co0 = cot * 32 + cog * 2;
        float r00 = fmaxf(T[0].x, 0.f), r01 = fmaxf(T[1].x, 0.f);
        float r10 = fmaxf(T[0].y, 0.f), r11 = fmaxf(T[1].y, 0.f);
        v2f o0; o0.x = r00; o0.y = r01;
        v2f o1; o1.x = r10; o1.y = r11;
        size_t base = (size_t)img * 524288 + (size_t)oy * 64 + xbase + 2 * xg;
        *(v2f*)&out[base + (size_t)co0 * 4096] = o0;
        *(v2f*)&out[base + (size_t)(co0 + 1) * 4096] = o1;
    }
}

// ---------------- conv4: 128->4, 3x3, s1, p1 (unchanged from R12)
__global__ __launch_bounds__(256) void conv4_kernel(
    const float* __restrict__ h3, const float* __restrict__ w4,
    const float* __restrict__ b4, float* __restrict__ z, int b0) {
#pragma clang fp contract(off)
    __shared__ __align__(16) float Il3[8][3][66];
    __shared__ __align__(16) float w4l[4608];
    const int tid = threadIdx.x;
    const int wl = tid & 63, co = tid >> 6;
    const int h = blockIdx.x, bl = blockIdx.y;
    const float* inp = h3 + (size_t)bl * 524288;

    for (int it = 0; it < 18; ++it) {
        int e = tid + it * 256;
        if (e < 4608) w4l[e] = w4[e];
    }

    float ls[16];
    for (int L = 0; L < 16; ++L) {
        __syncthreads();
        for (int it = 0; it < 7; ++it) {
            int e = tid + it * 256;
            if (e < 1584) {
                int cil = e / 198;
                int rem = e - cil * 198;
                int ky = rem / 66, col = rem - ky * 66;
                int iy = h - 1 + ky, gx = col - 1;
                bool ok = ((unsigned)iy < 64u) && ((unsigned)gx < 64u);
                Il3[cil][ky][col] =
                    ok ? inp[(size_t)(8 * L + cil) * 4096 + iy * 64 + gx] : 0.f;
            }
        }
        __syncthreads();

        float r[8];
#pragma unroll
        for (int j = 0; j < 8; ++j) r[j] = 0.f;
#pragma unroll
        for (int i = 0; i < 9; ++i) {
#pragma unroll
            for (int j = 0; j < 8; ++j) {
                int kk = 8 * i + j;
                int cil = kk / 9, f = kk - 9 * cil;
                int ky = f / 3, kx = f - 3 * ky;
                float p = Il3[cil][ky][wl + kx] *
                          w4l[co * 1152 + (8 * L + cil) * 9 + f];
                r[j] = r[j] + p;
            }
        }
        float t01 = r[0] + r[1], t23 = r[2] + r[3];
        float t45 = r[4] + r[5], t67 = r[6] + r[7];
        ls[L] = (t01 + t23) + (t45 + t67);
    }

    float a01 = ls[0] + ls[1],  a23 = ls[2] + ls[3];
    float a45 = ls[4] + ls[5],  a67 = ls[6] + ls[7];
    float A = (a01 + a23) + (a45 + a67);
    float c01 = ls[8] + ls[9],  c23 = ls[10] + ls[11];
    float c45 = ls[12] + ls[13], c67 = ls[14] + ls[15];
    float B = (c01 + c23) + (c45 + c67);
    float tot = A + B;

    z[(size_t)(b0 + bl) * 16384 + (size_t)co * 4096 + (size_t)h * 64 + wl] =
        tot + b4[co];
}

// ---------------- VQ (unchanged from R12)
__global__ __launch_bounds__(256) void vq_kernel(
    const float* __restrict__ z, const float* __restrict__ emb,
    float* __restrict__ zq_out, float* __restrict__ idx_out,
    float* __restrict__ loss_out) {
#pragma clang fp contract(off)
    __shared__ float4 el[512];
    __shared__ float t3s[512];
    const int tid = threadIdx.x;
#pragma unroll
    for (int i = 0; i < 2; ++i) {
        int e = tid + i * 256;
        float4 v = ((const float4*)emb)[e];
        el[e] = v;
        float q0 = v.x * v.x, q1 = v.y * v.y, q2 = v.z * v.z, q3 = v.w * v.w;
        t3s[e] = ((q0 + q1) + q2) + q3;
    }
    __syncthreads();

    const int r = blockIdx.x * 256 + tid;
    float4 v = ((const float4*)z)[r];
    float q0 = v.x * v.x, q1 = v.y * v.y, q2 = v.z * v.z, q3 = v.w * v.w;
    float t1 = ((q0 + q1) + q2) + q3;

    float best = __builtin_inff();
    int bi = 0;
    for (int jj = 0; jj < 512; ++jj) {
        float4 e = el[jj];
        float t2 = fmaf(v.x, e.x, 0.f);
        t2 = fmaf(v.y, e.y, t2);
        t2 = fmaf(v.z, e.z, t2);
        t2 = fmaf(v.w, e.w, t2);
        float two_t2 = 2.f * t2;
        float d = (t1 - two_t2) + t3s[jj];
        if (d < best) { best = d; bi = jj; }
    }
    float4 q = el[bi];
    ((float4*)zq_out)[r] = q;
    idx_out[r] = (float)bi;

    double dx = (double)q.x - v.x, dy = (double)q.y - v.y;
    double dz2 = (double)q.z - v.z, dw = (double)q.w - v.w;
    double part = dx * dx + dy * dy + dz2 * dz2 + dw * dw;
#pragma unroll
    for (int off = 32; off > 0; off >>= 1) part += __shfl_down(part, off, 64);
    __shared__ double ps[4];
    if ((tid & 63) == 0) ps[tid >> 6] = part;
    __syncthreads();
    if (tid == 0) {
        double s = ps[0] + ps[1] + ps[2] + ps[3];
        atomicAdd(loss_out, (float)(s * (1.25 / 262144.0)));
    }
}

// ---------------------------------------------------------------------------
extern "C" void kernel_launch(void* const* d_in, const int* in_sizes, int n_in,
                              void* d_out, int out_size, void* d_ws, size_t ws_size,
                              hipStream_t stream) {
    const float* x   = (const float*)d_in[0];
    const float* w1  = (const float*)d_in[1];
    const float* b1  = (const float*)d_in[2];
    const float* w2  = (const float*)d_in[3];
    const float* b2  = (const float*)d_in[4];
    const float* w3  = (const float*)d_in[5];
    const float* b3  = (const float*)d_in[6];
    const float* w4  = (const float*)d_in[7];
    const float* b4  = (const float*)d_in[8];
    const float* emb = (const float*)d_in[9];
    float* out = (float*)d_out;

    float* ws = (float*)d_ws;
    // layout (floats): zb[262144] | wT2[131072] | wT3[262144]
    //                 | h1c[CH*4194304] | h2c[CH*2097152] | h3c[CH*524288]
    int CH = 4;
    while (CH > 1 &&
           ((size_t)655360u + (size_t)CH * 6815744u) * 4ull > ws_size)
        CH >>= 1;
    float* zb  = ws;
    float* wT2 = ws + 262144;
    float* wT3 = wT2 + 131072;
    float* h1c = wT3 + 262144;
    float* h2c = h1c + (size_t)CH * 4194304;
    float* h3c = h2c + (size_t)CH * 2097152;

    wt_kernel<<<1536, 256, 0, stream>>>(w2, w3, wT2, wT3);

    for (int b0 = 0; b0 < 16; b0 += CH) {
        conv1_kernel<<<dim3(4, 16, CH), 256, 0, stream>>>(
            x + (size_t)b0 * 262144, w1, b1, h1c);
        conv2_kernel<<<dim3(16, 128, CH), 256, 0, stream>>>(h1c, wT2, b2, h2c);
        conv3_kernel<<<dim3(8, 64, CH), 256, 0, stream>>>(h2c, wT3, b3, h3c);
        conv4_kernel<<<dim3(64, CH), 256, 0, stream>>>(h3c, w4, b4, zb, b0);
    }

    hipMemsetAsync(out + 262144, 0, sizeof(float), stream);  // loss accumulator
    vq_kernel<<<256, 256, 0, stream>>>(zb, emb, out, out + 262144 + 1, out + 262144);
}